// Round 1
// 705.733 us; speedup vs baseline: 1.0602x; 1.0602x over previous
//
#include <hip/hip_runtime.h>

// Problem constants
#define BN   64
#define LN   1024
#define DKN  64
#define PN   2047          // 2*L - 1
#define OUT_O_ELEMS ((size_t)BN * LN * DKN)   // 4,194,304
constexpr float kScale = 0.125f;              // 1/sqrt(64)

typedef short bf16x8 __attribute__((ext_vector_type(8)));
typedef float f32x4  __attribute__((ext_vector_type(4)));

__device__ __forceinline__ unsigned short f2b(float f) {       // round-half-up (~RNE quality)
  return (unsigned short)((__float_as_uint(f) + 0x8000u) >> 16);
}
__device__ __forceinline__ float b2f(unsigned short h) {
  return __uint_as_float(((unsigned)h) << 16);
}
__device__ __forceinline__ unsigned pk2(float x, float y) {    // two bf16 packed in a uint
  unsigned lo = (__float_as_uint(x) + 0x8000u) >> 16;
  unsigned hi = (__float_as_uint(y) + 0x8000u) & 0xFFFF0000u;
  return lo | hi;
}

union U8 { unsigned u[4]; bf16x8 v; };

__device__ __forceinline__ bf16x8 pack8(float4 a, float4 b) {
  U8 r;
  r.u[0] = pk2(a.x, a.y); r.u[1] = pk2(a.z, a.w);
  r.u[2] = pk2(b.x, b.y); r.u[3] = pk2(b.z, b.w);
  return r.v;
}

// ---------- mask dtype detection ----------
__global__ void flag_init(unsigned* f) { *f = 0u; }

__global__ void flag_scan(const unsigned* __restrict__ mw, unsigned* f) {
  int idx = blockIdx.x * 256 + threadIdx.x;
  unsigned bits = 0;
#pragma unroll
  for (int i = 0; i < 4; ++i) {
    unsigned wv = mw[idx * 4 + i];
    if (wv == 0x3F800000u) bits |= 2u;
    else if (wv > 1u)      bits |= 4u;
  }
  if (bits) atomicOr(f, bits);
}

// ---------- pre-pass: f32 -> bf16 conversions ----------
__global__ __launch_bounds__(256) void convert_f32_bf16(const float4* __restrict__ in,
                                                        uint2* __restrict__ outp) {
  int idx = blockIdx.x * 256 + threadIdx.x;
  float4 a = in[idx];
  outp[idx] = make_uint2(pk2(a.x, a.y), pk2(a.z, a.w));
}

// v [b][m][d] f32  ->  vt [b][d][m] bf16
__global__ __launch_bounds__(256) void transpose_v(const float4* __restrict__ vg,
                                                   short* __restrict__ vt) {
  __shared__ float tile[64 * 65];
  const int tid = threadIdx.x;
  const int b  = blockIdx.x >> 4;
  const int mt = blockIdx.x & 15;
  const size_t base = ((size_t)b * 1024 + mt * 64) * 16;   // float4 units
#pragma unroll
  for (int i = 0; i < 4; ++i) {
    int j = tid + (i << 8);
    float4 a = vg[base + j];
    float* d = &tile[(j >> 4) * 65 + ((j & 15) << 2)];
    d[0] = a.x; d[1] = a.y; d[2] = a.z; d[3] = a.w;
  }
  __syncthreads();
#pragma unroll
  for (int i = 0; i < 4; ++i) {
    int j  = tid + (i << 8);
    int d  = j >> 4;
    int mq = (j & 15) << 2;
    unsigned u0 = pk2(tile[(mq + 0) * 65 + d], tile[(mq + 1) * 65 + d]);
    unsigned u1 = pk2(tile[(mq + 2) * 65 + d], tile[(mq + 3) * 65 + d]);
    size_t idx = ((size_t)b * 64 + d) * 1024 + mt * 64 + mq;
    *(uint2*)(vt + idx) = make_uint2(u0, u1);
  }
}

// ---------- main fused kernel ----------
// Block: b fixed, 16 query rows. 256 threads = 4 waves.
// Phase 1 (no barriers): wave w computes S/E for m-subcolumns m0+16w+col over 16 tiles,
//   with distance-1 register double-buffering of the K/P/mask loads.
// Phase 2 (no barriers): wave w computes PV for d = 16w+col, V loads double-buffered,
//   attn-row stores interleaved with the MFMAs.
__global__ __launch_bounds__(256, 4)
void attn_kernel(const float* __restrict__ qf, const float* __restrict__ kf,
                 const float* __restrict__ vf, const float* __restrict__ pf,
                 const void* __restrict__ mask, const unsigned* __restrict__ flagp,
                 const short* __restrict__ k16, const short* __restrict__ p16,
                 const short* __restrict__ vt16,
                 float* __restrict__ out) {
  __shared__ short qA[16 * 72];
  __shared__ short qrA[16 * 72];
  __shared__ short E[16 * 1032];    // unnormalized exp(s), bf16
  __shared__ float rowSum[16];

  const int tid  = threadIdx.x;
  const int w    = tid >> 6;
  const int lane = tid & 63;
  const int col  = lane & 15;
  const int quad = lane >> 4;

  // XCD swizzle: all 64 row-tiles of one b land on the same XCD
  int p   = blockIdx.x;
  int xcd = p & 7;
  int qq  = p >> 3;
  int rt  = qq & 63;
  int bh  = qq >> 6;
  const int b  = (bh << 3) | xcd;
  const int l0 = rt << 4;

  unsigned mflag = flagp ? flagp[0] : 0u;
  const int mkind = (mflag & 4u) ? 1 : ((mflag & 2u) ? 2 : 0);  // 0=int32 1=u8 2=f32

  if (tid < 16) rowSum[tid] = 0.0f;

  // stage qA / qrA
  {
    const float4* qg = (const float4*)qf;
    int row = tid >> 4, c4 = tid & 15;
    float4 a  = qg[((size_t)b * LN + (l0 + row)) * 16 + c4];
    float4 r_ = qg[((size_t)b * LN + (LN - 1 - l0 - row)) * 16 + c4];
    *(uint2*)&qA[row * 72 + c4 * 4]  = make_uint2(pk2(a.x, a.y), pk2(a.z, a.w));
    *(uint2*)&qrA[row * 72 + c4 * 4] = make_uint2(pk2(r_.x, r_.y), pk2(r_.z, r_.w));
  }
  __syncthreads();

  // hoisted A-fragments: A[m=lane&15][k=quad*8+j]
  const bf16x8 aq0 = *(const bf16x8*)&qA[col * 72 + quad * 8];
  const bf16x8 aq1 = *(const bf16x8*)&qA[col * 72 + quad * 8 + 32];
  const bf16x8 ar0 = *(const bf16x8*)&qrA[col * 72 + quad * 8];
  const bf16x8 ar1 = *(const bf16x8*)&qrA[col * 72 + quad * 8 + 32];

  float sumr[4] = {0.f, 0.f, 0.f, 0.f};
  const int moff = (w << 4) + col;
  // mask base index for row i = quad*4 (element col offset added via mglob)
  const size_t mrow0 = (((size_t)b << 10) + (size_t)(l0 + (quad << 2))) << 10;

  // ---------------- Phase 1: scores + exp + E ----------------
  if (k16) {
    struct KPM { bf16x8 k0, k1, p00, p01, p10, p11; unsigned m[4]; };
    KPM A, Bf;

    auto LOAD = [&](int t, KPM& o) {
      const int m0 = t << 6, mglob = m0 + moff;
      const short* kr = k16 + ((size_t)b * LN + mglob) * DKN + quad * 8;
      o.k0 = *(const bf16x8*)kr;
      o.k1 = *(const bf16x8*)(kr + 32);
      int g0 = l0 + m0 + moff;                           // <= 2031, in range
      int g1 = g0 + 16; if (g1 > PN - 1) g1 = PN - 1;    // clamped row never consumed
      const short* pr0 = p16 + ((size_t)b * PN + g0) * DKN + quad * 8;
      const short* pr1 = p16 + ((size_t)b * PN + g1) * DKN + quad * 8;
      o.p00 = *(const bf16x8*)pr0;
      o.p01 = *(const bf16x8*)(pr0 + 32);
      o.p10 = *(const bf16x8*)pr1;
      o.p11 = *(const bf16x8*)(pr1 + 32);
      const size_t mi = mrow0 + (size_t)mglob;
      if (mkind == 1) {
        const unsigned char* mp = (const unsigned char*)mask + mi;
#pragma unroll
        for (int r = 0; r < 4; ++r) o.m[r] = mp[(size_t)r << 10];
      } else {  // int32 and f32 both: raw word, nonzero == masked (values are exactly 0/1/1.0f)
        const unsigned* mp = (const unsigned*)mask + mi;
#pragma unroll
        for (int r = 0; r < 4; ++r) o.m[r] = mp[(size_t)r << 10];
      }
    };

    auto COMP = [&](int t, KPM& o) {
      f32x4 qk = {0.f, 0.f, 0.f, 0.f};
      qk = __builtin_amdgcn_mfma_f32_16x16x32_bf16(aq0, o.k0, qk, 0, 0, 0);
      qk = __builtin_amdgcn_mfma_f32_16x16x32_bf16(aq1, o.k1, qk, 0, 0, 0);
      f32x4 ba = {0.f, 0.f, 0.f, 0.f}, bb = {0.f, 0.f, 0.f, 0.f};
      ba = __builtin_amdgcn_mfma_f32_16x16x32_bf16(ar0, o.p00, ba, 0, 0, 0);
      ba = __builtin_amdgcn_mfma_f32_16x16x32_bf16(ar1, o.p01, ba, 0, 0, 0);
      bb = __builtin_amdgcn_mfma_f32_16x16x32_bf16(ar0, o.p10, bb, 0, 0, 0);
      bb = __builtin_amdgcn_mfma_f32_16x16x32_bf16(ar1, o.p11, bb, 0, 0, 0);
      const int mglob = (t << 6) + moff;
#pragma unroll
      for (int r = 0; r < 4; ++r) {
        int i = (quad << 2) + r;               // local l row
        int o2 = i + col;                      // needed p-offset (<= 30)
        int srcLane = (lane & 48) | (o2 & 15);
        float va = __shfl(ba[r], srcLane);
        float vb = __shfl(bb[r], srcLane);
        float bias = (o2 < 16) ? va : vb;
        float s = (qk[r] + bias) * kScale;
        float e = o.m[r] ? 0.f : __expf(s);
        unsigned short eb = f2b(e);
        sumr[r] += b2f(eb);                    // sum what we actually store
        E[i * 1032 + mglob] = (short)eb;
      }
    };

    LOAD(0, A);
    for (int t = 0; t < 16; t += 2) {
      LOAD(t + 1, Bf);                 // prefetch next tile while computing current
      COMP(t, A);
      if (t < 14) LOAD(t + 2, A);
      COMP(t + 1, Bf);
    }
  } else {
    // fallback: f32 inputs, no prefetch
    for (int t = 0; t < 16; ++t) {
      const int m0 = t << 6, mglob = m0 + moff;
      int g0 = l0 + m0 + moff;
      int g1 = g0 + 16; if (g1 > PN - 1) g1 = PN - 1;
      const float4* kr = (const float4*)(kf + ((size_t)b * LN + mglob) * DKN);
      bf16x8 kb0 = pack8(kr[quad * 2], kr[quad * 2 + 1]);
      bf16x8 kb1 = pack8(kr[8 + quad * 2], kr[9 + quad * 2]);
      const float4* pr0 = (const float4*)(pf + ((size_t)b * PN + g0) * DKN);
      const float4* pr1 = (const float4*)(pf + ((size_t)b * PN + g1) * DKN);
      bf16x8 pb00 = pack8(pr0[quad * 2], pr0[quad * 2 + 1]);
      bf16x8 pb01 = pack8(pr0[8 + quad * 2], pr0[9 + quad * 2]);
      bf16x8 pb10 = pack8(pr1[quad * 2], pr1[quad * 2 + 1]);
      bf16x8 pb11 = pack8(pr1[8 + quad * 2], pr1[9 + quad * 2]);

      f32x4 qk = {0.f, 0.f, 0.f, 0.f};
      qk = __builtin_amdgcn_mfma_f32_16x16x32_bf16(aq0, kb0, qk, 0, 0, 0);
      qk = __builtin_amdgcn_mfma_f32_16x16x32_bf16(aq1, kb1, qk, 0, 0, 0);
      f32x4 ba = {0.f, 0.f, 0.f, 0.f}, bb = {0.f, 0.f, 0.f, 0.f};
      ba = __builtin_amdgcn_mfma_f32_16x16x32_bf16(ar0, pb00, ba, 0, 0, 0);
      ba = __builtin_amdgcn_mfma_f32_16x16x32_bf16(ar1, pb01, ba, 0, 0, 0);
      bb = __builtin_amdgcn_mfma_f32_16x16x32_bf16(ar0, pb10, bb, 0, 0, 0);
      bb = __builtin_amdgcn_mfma_f32_16x16x32_bf16(ar1, pb11, bb, 0, 0, 0);

#pragma unroll
      for (int r = 0; r < 4; ++r) {
        int i = (quad << 2) + r;
        int o2 = i + col;
        int srcLane = (lane & 48) | (o2 & 15);
        float va = __shfl(ba[r], srcLane);
        float vb = __shfl(bb[r], srcLane);
        float bias = (o2 < 16) ? va : vb;
        float s = (qk[r] + bias) * kScale;
        size_t mi = mrow0 + ((size_t)r << 10) + (size_t)mglob;
        unsigned mu = (mkind == 1) ? (unsigned)((const unsigned char*)mask)[mi]
                                   : ((const unsigned*)mask)[mi];
        float e = mu ? 0.f : __expf(s);
        unsigned short eb = f2b(e);
        sumr[r] += b2f(eb);
        E[i * 1032 + mglob] = (short)eb;
      }
    }
  }

  // ---- row-sum reduction ----
#pragma unroll
  for (int r = 0; r < 4; ++r) {
    float vsum = sumr[r];
    vsum += __shfl_xor(vsum, 1);
    vsum += __shfl_xor(vsum, 2);
    vsum += __shfl_xor(vsum, 4);
    vsum += __shfl_xor(vsum, 8);
    if (col == 0) atomicAdd(&rowSum[(quad << 2) + r], vsum);
  }
  __syncthreads();                            // E + rowSum visible (only barrier after staging)

  // ---------------- Phase 2: PV + attn write ----------------
  f32x4 acc = {0.f, 0.f, 0.f, 0.f};           // O[l=quad*4+r][d=16w+col]
  const int drow = moff;
  float* outA = out + OUT_O_ELEMS;
  const size_t aBase = (((size_t)b << 10) + (size_t)l0) << 10;

  auto WROW = [&](int t) {                     // write attn row l0+t (1024 f32)
    float inv = 1.0f / rowSum[t];
    const ushort4 ev = *(const ushort4*)&E[t * 1032 + (tid << 2)];
    float4 o4;
    o4.x = b2f(ev.x) * inv;
    o4.y = b2f(ev.y) * inv;
    o4.z = b2f(ev.z) * inv;
    o4.w = b2f(ev.w) * inv;
    *(float4*)&outA[aBase + ((size_t)t << 10) + (size_t)(tid << 2)] = o4;
  };

  if (vt16) {
    const short* vbase = vt16 + ((size_t)b * 64 + drow) * 1024 + quad * 8;
    bf16x8 v0A = *(const bf16x8*)vbase;
    bf16x8 v1A = *(const bf16x8*)(vbase + 32);
    bf16x8 v0B, v1B;
    for (int t = 0; t < 16; t += 2) {
      { const short* vr = vbase + ((t + 1) << 6);      // prefetch t+1
        v0B = *(const bf16x8*)vr; v1B = *(const bf16x8*)(vr + 32); }
      { const int m0 = t << 6;
        bf16x8 ea0 = *(const bf16x8*)&E[col * 1032 + m0 + quad * 8];
        bf16x8 ea1 = *(const bf16x8*)&E[col * 1032 + m0 + 32 + quad * 8];
        acc = __builtin_amdgcn_mfma_f32_16x16x32_bf16(ea0, v0A, acc, 0, 0, 0);
        acc = __builtin_amdgcn_mfma_f32_16x16x32_bf16(ea1, v1A, acc, 0, 0, 0);
        WROW(t); }                                     // stream attn row under V-load latency
      if (t < 14) { const short* vr = vbase + ((t + 2) << 6);   // prefetch t+2
        v0A = *(const bf16x8*)vr; v1A = *(const bf16x8*)(vr + 32); }
      { const int m0 = (t + 1) << 6;
        bf16x8 ea0 = *(const bf16x8*)&E[col * 1032 + m0 + quad * 8];
        bf16x8 ea1 = *(const bf16x8*)&E[col * 1032 + m0 + 32 + quad * 8];
        acc = __builtin_amdgcn_mfma_f32_16x16x32_bf16(ea0, v0B, acc, 0, 0, 0);
        acc = __builtin_amdgcn_mfma_f32_16x16x32_bf16(ea1, v1B, acc, 0, 0, 0);
        WROW(t + 1); }
    }
  } else {
    for (int t = 0; t < 16; ++t) {
      const int m0 = t << 6;
      const float* vc = vf + ((size_t)b * LN + m0) * DKN + drow;
      U8 t0, t1;
#pragma unroll
      for (int j = 0; j < 4; ++j) {
        t0.u[j] = pk2(vc[(quad * 8 + 2 * j) * 64],      vc[(quad * 8 + 2 * j + 1) * 64]);
        t1.u[j] = pk2(vc[(32 + quad * 8 + 2 * j) * 64], vc[(32 + quad * 8 + 2 * j + 1) * 64]);
      }
      bf16x8 ea0 = *(const bf16x8*)&E[col * 1032 + m0 + quad * 8];
      bf16x8 ea1 = *(const bf16x8*)&E[col * 1032 + m0 + 32 + quad * 8];
      acc = __builtin_amdgcn_mfma_f32_16x16x32_bf16(ea0, t0.v, acc, 0, 0, 0);
      acc = __builtin_amdgcn_mfma_f32_16x16x32_bf16(ea1, t1.v, acc, 0, 0, 0);
    }
    for (int t = 0; t < 16; ++t) WROW(t);
  }

  // ---- write O ----
#pragma unroll
  for (int r = 0; r < 4; ++r) {
    int i = (quad << 2) + r;
    out[(((size_t)b << 10) + (size_t)(l0 + i)) * 64 + drow] = acc[r] * (1.0f / rowSum[i]);
  }
}

extern "C" void kernel_launch(void* const* d_in, const int* in_sizes, int n_in,
                              void* d_out, int out_size, void* d_ws, size_t ws_size,
                              hipStream_t stream) {
  const float* q   = (const float*)d_in[0];
  const float* k   = (const float*)d_in[1];
  const float* v   = (const float*)d_in[2];
  const float* pos = (const float*)d_in[3];
  const void* mask = d_in[4];
  float* out = (float*)d_out;

  unsigned* flag = nullptr;
  if (ws_size >= 256) {
    flag = (unsigned*)d_ws;
    flag_init<<<1, 1, 0, stream>>>(flag);
    flag_scan<<<64, 256, 0, stream>>>((const unsigned*)mask, flag);
  }

  // bf16 pre-pass workspace layout (after 256B flag area)
  const size_t kElems  = (size_t)BN * LN * DKN;   // 4,194,304
  const size_t pElems  = (size_t)BN * PN * DKN;   // 8,384,512
  const size_t offK    = 256;
  const size_t offP    = offK + kElems * 2;       // 8,388,608
  const size_t offVT   = offP + pElems * 2;       // 16,769,024
  const size_t wsNeed  = offVT + kElems * 2;

  short *k16 = nullptr, *p16 = nullptr, *vt16 = nullptr;
  if (ws_size >= wsNeed) {
    char* base = (char*)d_ws;
    k16  = (short*)(base + offK);
    p16  = (short*)(base + offP);
    vt16 = (short*)(base + offVT);
    convert_f32_bf16<<<(int)(kElems / 1024), 256, 0, stream>>>((const float4*)k,   (uint2*)k16);
    convert_f32_bf16<<<(int)(pElems / 1024), 256, 0, stream>>>((const float4*)pos, (uint2*)p16);
    transpose_v<<<BN * 16, 256, 0, stream>>>((const float4*)v, vt16);
  }

  attn_kernel<<<BN * (LN / 16), 256, 0, stream>>>(q, k, v, pos, mask, flag,
                                                  k16, p16, vt16, out);
}

// Round 2
// 698.032 us; speedup vs baseline: 1.0719x; 1.0110x over previous
//
#include <hip/hip_runtime.h>

// Problem constants
#define BN   64
#define LN   1024
#define DKN  64
#define PN   2047          // 2*L - 1
#define OUT_O_ELEMS ((size_t)BN * LN * DKN)   // 4,194,304
constexpr float kScale = 0.125f;              // 1/sqrt(64)

typedef short bf16x8 __attribute__((ext_vector_type(8)));
typedef float f32x4  __attribute__((ext_vector_type(4)));

__device__ __forceinline__ unsigned short f2b(float f) {       // round-half-up (~RNE quality)
  return (unsigned short)((__float_as_uint(f) + 0x8000u) >> 16);
}
__device__ __forceinline__ float b2f(unsigned short h) {
  return __uint_as_float(((unsigned)h) << 16);
}
__device__ __forceinline__ unsigned pk2(float x, float y) {    // two bf16 packed in a uint
  unsigned lo = (__float_as_uint(x) + 0x8000u) >> 16;
  unsigned hi = (__float_as_uint(y) + 0x8000u) & 0xFFFF0000u;
  return lo | hi;
}

union U8 { unsigned u[4]; bf16x8 v; };

__device__ __forceinline__ bf16x8 pack8(float4 a, float4 b) {
  U8 r;
  r.u[0] = pk2(a.x, a.y); r.u[1] = pk2(a.z, a.w);
  r.u[2] = pk2(b.x, b.y); r.u[3] = pk2(b.z, b.w);
  return r.v;
}

// ---------- mask dtype detection ----------
__global__ void flag_init(unsigned* f) { *f = 0u; }

__global__ void flag_scan(const unsigned* __restrict__ mw, unsigned* f) {
  int idx = blockIdx.x * 256 + threadIdx.x;
  unsigned bits = 0;
#pragma unroll
  for (int i = 0; i < 4; ++i) {
    unsigned wv = mw[idx * 4 + i];
    if (wv == 0x3F800000u) bits |= 2u;
    else if (wv > 1u)      bits |= 4u;
  }
  if (bits) atomicOr(f, bits);
}

// ---------- pre-pass: f32 -> bf16 conversions (k and pos fused in one launch) ----------
__global__ __launch_bounds__(256) void convert2_f32_bf16(const float4* __restrict__ a,
                                                         uint2* __restrict__ oa, int na,
                                                         const float4* __restrict__ bsrc,
                                                         uint2* __restrict__ ob) {
  int idx = blockIdx.x * 256 + threadIdx.x;
  if (idx < na) {
    float4 x = a[idx];
    oa[idx] = make_uint2(pk2(x.x, x.y), pk2(x.z, x.w));
  } else {
    int j = idx - na;
    float4 x = bsrc[j];
    ob[j] = make_uint2(pk2(x.x, x.y), pk2(x.z, x.w));
  }
}

// v [b][m][d] f32  ->  vt [b][d][m] bf16
__global__ __launch_bounds__(256) void transpose_v(const float4* __restrict__ vg,
                                                   short* __restrict__ vt) {
  __shared__ float tile[64 * 65];
  const int tid = threadIdx.x;
  const int b  = blockIdx.x >> 4;
  const int mt = blockIdx.x & 15;
  const size_t base = ((size_t)b * 1024 + mt * 64) * 16;   // float4 units
#pragma unroll
  for (int i = 0; i < 4; ++i) {
    int j = tid + (i << 8);
    float4 a = vg[base + j];
    float* d = &tile[(j >> 4) * 65 + ((j & 15) << 2)];
    d[0] = a.x; d[1] = a.y; d[2] = a.z; d[3] = a.w;
  }
  __syncthreads();
#pragma unroll
  for (int i = 0; i < 4; ++i) {
    int j  = tid + (i << 8);
    int d  = j >> 4;
    int mq = (j & 15) << 2;
    unsigned u0 = pk2(tile[(mq + 0) * 65 + d], tile[(mq + 1) * 65 + d]);
    unsigned u1 = pk2(tile[(mq + 2) * 65 + d], tile[(mq + 3) * 65 + d]);
    size_t idx = ((size_t)b * 64 + d) * 1024 + mt * 64 + mq;
    *(uint2*)(vt + idx) = make_uint2(u0, u1);
  }
}

// ---------- main fused kernel ----------
// Block: b fixed, 16 query rows. 256 threads = 4 waves.
// LDS = E only (16x1024 bf16 = 32768 B exactly -> 5 blocks/CU).
// E is XOR-swizzled: logical E[i][m] stored at short index i*1024 + (m ^ ((i&7)<<3))
//   -> bank-balanced ds_read_b128 in phase 2 and ds_read_b64 in the attn tail.
// Row sums: no LDS/atomics. Every wave reads ALL of E in phase 2, so each wave
// redundantly accumulates full row sums from its own fragments; 2x shfl_xor
// finishes the per-row sum; __shfl redistributes 1/sum where needed.
__global__ __launch_bounds__(256, 8)   // force VGPR<=64: keeps 8-wave/SIMD slab, LDS gives 5 blocks/CU
void attn_kernel(const float* __restrict__ qf, const float* __restrict__ kf,
                 const float* __restrict__ vf, const float* __restrict__ pf,
                 const void* __restrict__ mask, const unsigned* __restrict__ flagp,
                 const short* __restrict__ k16, const short* __restrict__ p16,
                 const short* __restrict__ vt16,
                 float* __restrict__ out) {
  __shared__ short E[16 * 1024];    // unnormalized exp(s), bf16, swizzled

  const int tid  = threadIdx.x;
  const int w    = tid >> 6;
  const int lane = tid & 63;
  const int col  = lane & 15;
  const int quad = lane >> 4;

  // XCD swizzle: all 64 row-tiles of one b land on the same XCD
  int p   = blockIdx.x;
  int xcd = p & 7;
  int qq  = p >> 3;
  int rt  = qq & 63;
  int bh  = qq >> 6;
  const int b  = (bh << 3) | xcd;
  const int l0 = rt << 4;

  unsigned mflag = flagp ? flagp[0] : 0u;
  const int mkind = (mflag & 4u) ? 1 : ((mflag & 2u) ? 2 : 0);  // 0=int32 1=u8 2=f32

  // Q fragments straight from global (no LDS staging, no barrier):
  // lane (col,quad) owns A[m=col][k=quad*8+j] -> reads 2 float4 per fragment.
  const float4* qg = (const float4*)qf;
  const size_t qrow  = ((size_t)b * LN + (size_t)(l0 + col)) * 16 + (size_t)(quad * 2);
  const size_t qrrow = ((size_t)b * LN + (size_t)(LN - 1 - l0 - col)) * 16 + (size_t)(quad * 2);
  const bf16x8 aq0 = pack8(qg[qrow],      qg[qrow + 1]);
  const bf16x8 aq1 = pack8(qg[qrow + 8],  qg[qrow + 9]);
  const bf16x8 ar0 = pack8(qg[qrrow],     qg[qrrow + 1]);
  const bf16x8 ar1 = pack8(qg[qrrow + 8], qg[qrrow + 9]);

  const int moff = (w << 4) + col;
  const size_t mrow0 = (((size_t)b << 10) + (size_t)(l0 + (quad << 2))) << 10;

  // ---------------- Phase 1: scores + exp + E ----------------
  if (k16) {
    struct KPM { bf16x8 k0, k1, p00, p01, p10, p11; unsigned m[4]; };
    KPM A, Bf;

    auto LOAD = [&](int t, KPM& o) {
      const int m0 = t << 6, mglob = m0 + moff;
      const short* kr = k16 + ((size_t)b * LN + mglob) * DKN + quad * 8;
      o.k0 = *(const bf16x8*)kr;
      o.k1 = *(const bf16x8*)(kr + 32);
      int g0 = l0 + m0 + moff;                           // <= 2031, in range
      int g1 = g0 + 16; if (g1 > PN - 1) g1 = PN - 1;    // clamped row never consumed
      const short* pr0 = p16 + ((size_t)b * PN + g0) * DKN + quad * 8;
      const short* pr1 = p16 + ((size_t)b * PN + g1) * DKN + quad * 8;
      o.p00 = *(const bf16x8*)pr0;
      o.p01 = *(const bf16x8*)(pr0 + 32);
      o.p10 = *(const bf16x8*)pr1;
      o.p11 = *(const bf16x8*)(pr1 + 32);
      const size_t mi = mrow0 + (size_t)mglob;
      if (mkind == 1) {
        const unsigned char* mp = (const unsigned char*)mask + mi;
#pragma unroll
        for (int r = 0; r < 4; ++r) o.m[r] = __builtin_nontemporal_load(mp + ((size_t)r << 10));
      } else {  // int32 and f32 both: raw word, nonzero == masked
        const unsigned* mp = (const unsigned*)mask + mi;
#pragma unroll
        for (int r = 0; r < 4; ++r) o.m[r] = __builtin_nontemporal_load(mp + ((size_t)r << 10));
      }
    };

    auto COMP = [&](int t, KPM& o) {
      f32x4 qk = {0.f, 0.f, 0.f, 0.f};
      qk = __builtin_amdgcn_mfma_f32_16x16x32_bf16(aq0, o.k0, qk, 0, 0, 0);
      qk = __builtin_amdgcn_mfma_f32_16x16x32_bf16(aq1, o.k1, qk, 0, 0, 0);
      f32x4 ba = {0.f, 0.f, 0.f, 0.f}, bb = {0.f, 0.f, 0.f, 0.f};
      ba = __builtin_amdgcn_mfma_f32_16x16x32_bf16(ar0, o.p00, ba, 0, 0, 0);
      ba = __builtin_amdgcn_mfma_f32_16x16x32_bf16(ar1, o.p01, ba, 0, 0, 0);
      bb = __builtin_amdgcn_mfma_f32_16x16x32_bf16(ar0, o.p10, bb, 0, 0, 0);
      bb = __builtin_amdgcn_mfma_f32_16x16x32_bf16(ar1, o.p11, bb, 0, 0, 0);
      const int mglob = (t << 6) + moff;
#pragma unroll
      for (int r = 0; r < 4; ++r) {
        int i = (quad << 2) + r;               // local l row
        int o2 = i + col;                      // needed p-offset (<= 30)
        int srcLane = (lane & 48) | (o2 & 15);
        float va = __shfl(ba[r], srcLane);
        float vb = __shfl(bb[r], srcLane);
        float bias = (o2 < 16) ? va : vb;
        float s = (qk[r] + bias) * kScale;
        float e = o.m[r] ? 0.f : __expf(s);
        E[i * 1024 + (mglob ^ ((i & 7) << 3))] = (short)f2b(e);
      }
    };

    LOAD(0, A);
    for (int t = 0; t < 16; t += 2) {
      LOAD(t + 1, Bf);                 // prefetch next tile while computing current
      COMP(t, A);
      if (t < 14) LOAD(t + 2, A);
      COMP(t + 1, Bf);
    }
  } else {
    // fallback: f32 inputs, no prefetch
    for (int t = 0; t < 16; ++t) {
      const int m0 = t << 6, mglob = m0 + moff;
      int g0 = l0 + m0 + moff;
      int g1 = g0 + 16; if (g1 > PN - 1) g1 = PN - 1;
      const float4* kr = (const float4*)(kf + ((size_t)b * LN + mglob) * DKN);
      bf16x8 kb0 = pack8(kr[quad * 2], kr[quad * 2 + 1]);
      bf16x8 kb1 = pack8(kr[8 + quad * 2], kr[9 + quad * 2]);
      const float4* pr0 = (const float4*)(pf + ((size_t)b * PN + g0) * DKN);
      const float4* pr1 = (const float4*)(pf + ((size_t)b * PN + g1) * DKN);
      bf16x8 pb00 = pack8(pr0[quad * 2], pr0[quad * 2 + 1]);
      bf16x8 pb01 = pack8(pr0[8 + quad * 2], pr0[9 + quad * 2]);
      bf16x8 pb10 = pack8(pr1[quad * 2], pr1[quad * 2 + 1]);
      bf16x8 pb11 = pack8(pr1[8 + quad * 2], pr1[9 + quad * 2]);

      f32x4 qk = {0.f, 0.f, 0.f, 0.f};
      qk = __builtin_amdgcn_mfma_f32_16x16x32_bf16(aq0, kb0, qk, 0, 0, 0);
      qk = __builtin_amdgcn_mfma_f32_16x16x32_bf16(aq1, kb1, qk, 0, 0, 0);
      f32x4 ba = {0.f, 0.f, 0.f, 0.f}, bb = {0.f, 0.f, 0.f, 0.f};
      ba = __builtin_amdgcn_mfma_f32_16x16x32_bf16(ar0, pb00, ba, 0, 0, 0);
      ba = __builtin_amdgcn_mfma_f32_16x16x32_bf16(ar1, pb01, ba, 0, 0, 0);
      bb = __builtin_amdgcn_mfma_f32_16x16x32_bf16(ar0, pb10, bb, 0, 0, 0);
      bb = __builtin_amdgcn_mfma_f32_16x16x32_bf16(ar1, pb11, bb, 0, 0, 0);

#pragma unroll
      for (int r = 0; r < 4; ++r) {
        int i = (quad << 2) + r;
        int o2 = i + col;
        int srcLane = (lane & 48) | (o2 & 15);
        float va = __shfl(ba[r], srcLane);
        float vb = __shfl(bb[r], srcLane);
        float bias = (o2 < 16) ? va : vb;
        float s = (qk[r] + bias) * kScale;
        size_t mi = mrow0 + ((size_t)r << 10) + (size_t)mglob;
        unsigned mu = (mkind == 1) ? (unsigned)((const unsigned char*)mask)[mi]
                                   : ((const unsigned*)mask)[mi];
        float e = mu ? 0.f : __expf(s);
        E[i * 1024 + (mglob ^ ((i & 7) << 3))] = (short)f2b(e);
      }
    }
  }
  __syncthreads();                            // E visible to all waves (only barrier)

  // ---------------- Phase 2: PV + redundant row sums ----------------
  f32x4 acc = {0.f, 0.f, 0.f, 0.f};           // O[l=quad*4+r][d=16w+col]
  float sLo = 0.f, sHi = 0.f;                 // row-sum partials for row = col
  const int drow = moff;
  const int esw  = (col & 7) << 3;

  auto EAT = [&](bf16x8 ev) {                 // accumulate row-sum from an E fragment
    U8 u; u.v = ev;
#pragma unroll
    for (int j = 0; j < 4; ++j) {
      sLo += __uint_as_float(u.u[j] << 16);
      sHi += __uint_as_float(u.u[j] & 0xFFFF0000u);
    }
  };

  if (vt16) {
    const short* vbase = vt16 + ((size_t)b * 64 + drow) * 1024 + quad * 8;
    bf16x8 v0A = *(const bf16x8*)vbase;
    bf16x8 v1A = *(const bf16x8*)(vbase + 32);
    bf16x8 v0B, v1B;
    for (int t = 0; t < 16; t += 2) {
      { const short* vr = vbase + ((t + 1) << 6);      // prefetch t+1
        v0B = *(const bf16x8*)vr; v1B = *(const bf16x8*)(vr + 32); }
      { const int m0 = t << 6;
        bf16x8 ea0 = *(const bf16x8*)&E[col * 1024 + ((m0 + quad * 8) ^ esw)];
        bf16x8 ea1 = *(const bf16x8*)&E[col * 1024 + ((m0 + 32 + quad * 8) ^ esw)];
        acc = __builtin_amdgcn_mfma_f32_16x16x32_bf16(ea0, v0A, acc, 0, 0, 0);
        acc = __builtin_amdgcn_mfma_f32_16x16x32_bf16(ea1, v1A, acc, 0, 0, 0);
        EAT(ea0); EAT(ea1); }
      if (t < 14) { const short* vr = vbase + ((t + 2) << 6);   // prefetch t+2
        v0A = *(const bf16x8*)vr; v1A = *(const bf16x8*)(vr + 32); }
      { const int m0 = (t + 1) << 6;
        bf16x8 ea0 = *(const bf16x8*)&E[col * 1024 + ((m0 + quad * 8) ^ esw)];
        bf16x8 ea1 = *(const bf16x8*)&E[col * 1024 + ((m0 + 32 + quad * 8) ^ esw)];
        acc = __builtin_amdgcn_mfma_f32_16x16x32_bf16(ea0, v0B, acc, 0, 0, 0);
        acc = __builtin_amdgcn_mfma_f32_16x16x32_bf16(ea1, v1B, acc, 0, 0, 0);
        EAT(ea0); EAT(ea1); }
    }
  } else {
    for (int t = 0; t < 16; ++t) {
      const int m0 = t << 6;
      const float* vc = vf + ((size_t)b * LN + m0) * DKN + drow;
      U8 t0, t1;
#pragma unroll
      for (int j = 0; j < 4; ++j) {
        t0.u[j] = pk2(vc[(quad * 8 + 2 * j) * 64],      vc[(quad * 8 + 2 * j + 1) * 64]);
        t1.u[j] = pk2(vc[(32 + quad * 8 + 2 * j) * 64], vc[(32 + quad * 8 + 2 * j + 1) * 64]);
      }
      bf16x8 ea0 = *(const bf16x8*)&E[col * 1024 + ((m0 + quad * 8) ^ esw)];
      bf16x8 ea1 = *(const bf16x8*)&E[col * 1024 + ((m0 + 32 + quad * 8) ^ esw)];
      acc = __builtin_amdgcn_mfma_f32_16x16x32_bf16(ea0, t0.v, acc, 0, 0, 0);
      acc = __builtin_amdgcn_mfma_f32_16x16x32_bf16(ea1, t1.v, acc, 0, 0, 0);
      EAT(ea0); EAT(ea1);
    }
  }

  // finish row sums: combine the 4 quads that share this col
  float s = sLo + sHi;
  s += __shfl_xor(s, 16);
  s += __shfl_xor(s, 32);
  const float invS = 1.0f / s;                // per-lane: 1/sum of row `col`

  // ---- write O ----
#pragma unroll
  for (int r = 0; r < 4; ++r) {
    int i = (quad << 2) + r;
    float invi = __shfl(invS, (lane & 48) | i);
    out[(((size_t)b << 10) + (size_t)(l0 + i)) * 64 + drow] = acc[r] * invi;
  }

  // ---- write attn (streaming tail, nontemporal) ----
  float* outA = out + OUT_O_ELEMS;
  const size_t aBase = (((size_t)b << 10) + (size_t)l0) << 10;
  for (int t = 0; t < 16; ++t) {
    float inv = __shfl(invS, (lane & 48) | t);
    const ushort4 ev = *(const ushort4*)&E[t * 1024 + ((tid << 2) ^ ((t & 7) << 3))];
    f32x4 o4;
    o4[0] = b2f(ev.x) * inv;
    o4[1] = b2f(ev.y) * inv;
    o4[2] = b2f(ev.z) * inv;
    o4[3] = b2f(ev.w) * inv;
    __builtin_nontemporal_store(o4, (f32x4*)&outA[aBase + ((size_t)t << 10) + (size_t)(tid << 2)]);
  }
}

extern "C" void kernel_launch(void* const* d_in, const int* in_sizes, int n_in,
                              void* d_out, int out_size, void* d_ws, size_t ws_size,
                              hipStream_t stream) {
  const float* q   = (const float*)d_in[0];
  const float* k   = (const float*)d_in[1];
  const float* v   = (const float*)d_in[2];
  const float* pos = (const float*)d_in[3];
  const void* mask = d_in[4];
  float* out = (float*)d_out;

  unsigned* flag = nullptr;
  if (ws_size >= 256) {
    flag = (unsigned*)d_ws;
    flag_init<<<1, 1, 0, stream>>>(flag);
    flag_scan<<<64, 256, 0, stream>>>((const unsigned*)mask, flag);
  }

  // bf16 pre-pass workspace layout (after 256B flag area)
  const size_t kElems  = (size_t)BN * LN * DKN;   // 4,194,304
  const size_t pElems  = (size_t)BN * PN * DKN;   // 8,384,512
  const size_t offK    = 256;
  const size_t offP    = offK + kElems * 2;       // 8,388,608
  const size_t offVT   = offP + pElems * 2;       // 16,769,024
  const size_t wsNeed  = offVT + kElems * 2;

  short *k16 = nullptr, *p16 = nullptr, *vt16 = nullptr;
  if (ws_size >= wsNeed) {
    char* base = (char*)d_ws;
    k16  = (short*)(base + offK);
    p16  = (short*)(base + offP);
    vt16 = (short*)(base + offVT);
    const int na = (int)(kElems / 4);             // float4 count for k
    const int nb = (int)(pElems / 4);             // float4 count for pos
    convert2_f32_bf16<<<(na + nb) / 256, 256, 0, stream>>>((const float4*)k, (uint2*)k16, na,
                                                           (const float4*)pos, (uint2*)p16);
    transpose_v<<<BN * 16, 256, 0, stream>>>((const float4*)v, vt16);
  }

  attn_kernel<<<BN * (LN / 16), 256, 0, stream>>>(q, k, v, pos, mask, flag,
                                                  k16, p16, vt16, out);
}